// Round 1
// baseline (589.401 us; speedup 1.0000x reference)
//
#include <hip/hip_runtime.h>
#include <stdint.h>
#include <stddef.h>

#define B_ 4
#define S_ 2048
#define D_ 2048
#define NH 16
#define NKV 4
#define HD 128
#define QKV_N 3072
#define ROWS (B_*S_)

typedef unsigned short u16;
typedef __attribute__((ext_vector_type(8))) unsigned short u16x8;
typedef __attribute__((ext_vector_type(8))) __bf16 bf16x8;
typedef __attribute__((ext_vector_type(4))) float f32x4;

__device__ __forceinline__ u16 f2bf(float f) {
  unsigned u = __builtin_bit_cast(unsigned, f);
  return (u16)((u + 0x7fffu + ((u >> 16) & 1u)) >> 16);
}
__device__ __forceinline__ float bf2f(u16 h) {
  return __builtin_bit_cast(float, (unsigned)h << 16);
}
__device__ __forceinline__ f32x4 mfma16(u16x8 a, u16x8 b, f32x4 c) {
  return __builtin_amdgcn_mfma_f32_16x16x32_bf16(
      __builtin_bit_cast(bf16x8, a), __builtin_bit_cast(bf16x8, b), c, 0, 0, 0);
}
__device__ __forceinline__ void gld16(const void* g, void* l) {
  __builtin_amdgcn_global_load_lds(
      (const __attribute__((address_space(1))) void*)g,
      (__attribute__((address_space(3))) void*)l, 16, 0, 0);
}

// ---------- elementwise cast x -> bf16 ----------
__global__ __launch_bounds__(256) void k_cast_x(const float* __restrict__ x, u16* __restrict__ xb) {
  int i = blockIdx.x * 256 + threadIdx.x;
  float4 v = ((const float4*)x)[i];
  union { u16 u[4]; uint2 p; } o;
  o.u[0] = f2bf(v.x); o.u[1] = f2bf(v.y); o.u[2] = f2bf(v.z); o.u[3] = f2bf(v.w);
  ((uint2*)xb)[i] = o.p;
}

// ---------- tiled transpose+cast: w[K][N] fp32 -> wt[N][K(=2048 pitch)] bf16 ----------
__global__ __launch_bounds__(256) void k_wt(const float* __restrict__ w, u16* __restrict__ wt, int K, int N) {
  __shared__ float tile[32][33];
  int kb = blockIdx.y * 32, nb = blockIdx.x * 32;
  int tx = threadIdx.x, ty = threadIdx.y;
#pragma unroll
  for (int j = 0; j < 32; j += 8)
    tile[ty + j][tx] = w[(size_t)(kb + ty + j) * N + nb + tx];
  __syncthreads();
#pragma unroll
  for (int j = 0; j < 32; j += 8)
    wt[(size_t)(nb + ty + j) * K + kb + tx] = f2bf(tile[tx][ty + j]);
}

// ---------- m97-style GEMM: C[M][NT] = A[M][2048] * Bt[NT][2048]^T ----------
template<int NT, bool F32OUT>
__global__ __launch_bounds__(256) void k_gemm(const u16* __restrict__ A, const u16* __restrict__ Bt,
                                              void* __restrict__ C) {
  const int K = 2048;
  __shared__ u16 As[128 * 32];
  __shared__ u16 Bs[128 * 32];
  int mb = blockIdx.y * 128, nb = blockIdx.x * 128;
  int t = threadIdx.x;
  int l = t & 63, lane16 = l & 15, quad = l >> 4;
  int w = t >> 6;
  int wm = (w >> 1) * 64, wn = (w & 1) * 64;
  f32x4 acc[4][4] = {};
  for (int k0 = 0; k0 < K; k0 += 32) {
#pragma unroll
    for (int p = 0; p < 2; ++p) {
      int lin = p * 256 + t;
      int row = lin >> 2, ch = lin & 3;
      gld16(A  + (size_t)(mb + row) * K + k0 + ch * 8, As + (p * 256 + (t & 192)) * 8);
      gld16(Bt + (size_t)(nb + row) * K + k0 + ch * 8, Bs + (p * 256 + (t & 192)) * 8);
    }
    __syncthreads();
    u16x8 af[4], bf[4];
#pragma unroll
    for (int mt = 0; mt < 4; ++mt)
      af[mt] = *(const u16x8*)(As + (wm + mt * 16 + lane16) * 32 + quad * 8);
#pragma unroll
    for (int nt = 0; nt < 4; ++nt)
      bf[nt] = *(const u16x8*)(Bs + (wn + nt * 16 + lane16) * 32 + quad * 8);
#pragma unroll
    for (int mt = 0; mt < 4; ++mt)
#pragma unroll
      for (int nt = 0; nt < 4; ++nt)
        acc[mt][nt] = mfma16(af[mt], bf[nt], acc[mt][nt]);
    __syncthreads();
  }
#pragma unroll
  for (int mt = 0; mt < 4; ++mt)
#pragma unroll
    for (int nt = 0; nt < 4; ++nt)
#pragma unroll
      for (int r = 0; r < 4; ++r) {
        int row = mb + wm + mt * 16 + quad * 4 + r;
        int col = nb + wn + nt * 16 + lane16;
        if constexpr (F32OUT)
          ((float*)C)[(size_t)row * NT + col] = acc[mt][nt][r];
        else
          ((u16*)C)[(size_t)row * NT + col] = f2bf(acc[mt][nt][r]);
      }
}

// ---------- RoPE + scatter to per-head Q/K layouts ----------
__global__ __launch_bounds__(256) void k_rope(const u16* __restrict__ qkv, const float* __restrict__ fc,
                                              const float* __restrict__ fs, u16* __restrict__ Q,
                                              u16* __restrict__ Kk) {
  int row = blockIdx.x;            // b*S + s
  int b = row >> 11, s = row & 2047;
  int t = threadIdx.x;
#pragma unroll
  for (int j = 0; j < 5; ++j) {
    int p = t + j * 256;           // pair index, 0..1279
    int i = p & 63;
    float c = fc[s * 64 + i], sn = fs[s * 64 + i];
    if (p < 1024) {
      int h = p >> 6;
      unsigned pr = *(const unsigned*)(qkv + (size_t)row * QKV_N + h * 128 + 2 * i);
      float xr = bf2f((u16)(pr & 0xffff)), xi = bf2f((u16)(pr >> 16));
      size_t o = (((size_t)(b * NH + h) * S_) + s) * HD + 2 * i;
      unsigned out = (unsigned)f2bf(xr * c - xi * sn) | ((unsigned)f2bf(xr * sn + xi * c) << 16);
      *(unsigned*)(Q + o) = out;
    } else {
      int kh = (p - 1024) >> 6;
      unsigned pr = *(const unsigned*)(qkv + (size_t)row * QKV_N + 2048 + kh * 128 + 2 * i);
      float xr = bf2f((u16)(pr & 0xffff)), xi = bf2f((u16)(pr >> 16));
      size_t o = (((size_t)(b * NKV + kh) * S_) + s) * HD + 2 * i;
      unsigned out = (unsigned)f2bf(xr * c - xi * sn) | ((unsigned)f2bf(xr * sn + xi * c) << 16);
      *(unsigned*)(Kk + o) = out;
    }
  }
}

// ---------- V transpose: qkv[.,2560+kh*128+d] -> Vt[b][kh][d][s] ----------
__global__ __launch_bounds__(256) void k_vt(const u16* __restrict__ qkv, u16* __restrict__ Vt) {
  int blk = blockIdx.x;            // b*128 + kh*32 + sb
  int sb = blk & 31, kh = (blk >> 5) & 3, b = blk >> 7;
  int t = threadIdx.x;
  int d = t >> 1, sc = t & 1;
  int s0 = sb * 64 + sc * 32;
  u16 tmp[32];
#pragma unroll
  for (int i = 0; i < 32; ++i)
    tmp[i] = qkv[(size_t)(b * S_ + s0 + i) * QKV_N + 2560 + kh * 128 + d];
  size_t o = ((size_t)(b * NKV + kh) * HD + d) * S_ + s0;
#pragma unroll
  for (int i = 0; i < 32; i += 8)
    *(u16x8*)(Vt + o + i) = *(const u16x8*)(tmp + i);
}

// ---------- flash attention (causal, no-center online softmax) ----------
__global__ __launch_bounds__(256) void k_attn(const u16* __restrict__ Q, const u16* __restrict__ Kg,
                                              const u16* __restrict__ Vt, u16* __restrict__ O) {
  int bh = blockIdx.x & 63;
  int qb = 15 - (blockIdx.x >> 6);       // big-work blocks first
  int b = bh >> 4, h = bh & 15, kh = h >> 2;
  int t = threadIdx.x;
  int w = t >> 6, l = t & 63, lane16 = l & 15, quad = l >> 4;
  int q0 = qb * 128 + w * 32;            // this wave's 32 query rows

  __shared__ u16 Ks[32 * 136];
  __shared__ u16 Vs[128 * 40];
  __shared__ u16 Ps[4][32 * 40];
  u16* Pw = &Ps[w][0];

  const u16* Qh = Q  + ((size_t)(b * NH  + h ) * S_) * HD;
  const u16* Kh = Kg + ((size_t)(b * NKV + kh) * S_) * HD;
  const u16* Vh = Vt + ((size_t)(b * NKV + kh) * HD) * S_;

  u16x8 qf[2][4];
#pragma unroll
  for (int m = 0; m < 2; ++m)
#pragma unroll
    for (int kk = 0; kk < 4; ++kk)
      qf[m][kk] = *(const u16x8*)(Qh + (size_t)(q0 + m * 16 + lane16) * HD + kk * 32 + quad * 8);

  f32x4 acc[2][8] = {};
  float lsum[2][4] = {};
  const float SC = 0.1275174214f;        // log2(e)/sqrt(128)
  int ktiles = qb * 4 + 4;               // keys 0 .. qb*128+127
  for (int kt = 0; kt < ktiles; ++kt) {
    int kbase = kt * 32;
    __syncthreads();
#pragma unroll
    for (int p = 0; p < 2; ++p) {
      int lin = p * 256 + t;
      int key = lin >> 4, ch = lin & 15;
      *(u16x8*)(Ks + key * 136 + ch * 8) = *(const u16x8*)(Kh + (size_t)(kbase + key) * HD + ch * 8);
      int d = lin >> 2, kc = lin & 3;
      *(u16x8*)(Vs + d * 40 + kc * 8) = *(const u16x8*)(Vh + (size_t)d * S_ + kbase + kc * 8);
    }
    __syncthreads();
    // S = Q K^T
    f32x4 sAcc[2][2] = {};
#pragma unroll
    for (int n = 0; n < 2; ++n)
#pragma unroll
      for (int kk = 0; kk < 4; ++kk) {
        u16x8 kf = *(const u16x8*)(Ks + (n * 16 + lane16) * 136 + kk * 32 + quad * 8);
        sAcc[0][n] = mfma16(qf[0][kk], kf, sAcc[0][n]);
        sAcc[1][n] = mfma16(qf[1][kk], kf, sAcc[1][n]);
      }
    // exp + mask + P to LDS + row sums
    float pv[2][2][4];
#pragma unroll
    for (int m = 0; m < 2; ++m)
#pragma unroll
      for (int n = 0; n < 2; ++n)
#pragma unroll
        for (int r = 0; r < 4; ++r) {
          int key = kbase + n * 16 + lane16;
          int qrow = q0 + m * 16 + quad * 4 + r;
          float e = (key <= qrow) ? exp2f(sAcc[m][n][r] * SC) : 0.0f;
          pv[m][n][r] = e;
          Pw[(m * 16 + quad * 4 + r) * 40 + n * 16 + lane16] = f2bf(e);
        }
#pragma unroll
    for (int m = 0; m < 2; ++m)
#pragma unroll
      for (int r = 0; r < 4; ++r) {
        float rs = pv[m][0][r] + pv[m][1][r];
        rs += __shfl_xor(rs, 1); rs += __shfl_xor(rs, 2);
        rs += __shfl_xor(rs, 4); rs += __shfl_xor(rs, 8);
        lsum[m][r] += rs;
      }
    // O += P V
    u16x8 pf0 = *(const u16x8*)(Pw + (lane16) * 40 + quad * 8);
    u16x8 pf1 = *(const u16x8*)(Pw + (16 + lane16) * 40 + quad * 8);
#pragma unroll
    for (int nt = 0; nt < 8; ++nt) {
      u16x8 vf = *(const u16x8*)(Vs + (nt * 16 + lane16) * 40 + quad * 8);
      acc[0][nt] = mfma16(pf0, vf, acc[0][nt]);
      acc[1][nt] = mfma16(pf1, vf, acc[1][nt]);
    }
  }
  // epilogue: normalize, write [b][s][h*128+d]
#pragma unroll
  for (int m = 0; m < 2; ++m)
#pragma unroll
    for (int nt = 0; nt < 8; ++nt)
#pragma unroll
      for (int r = 0; r < 4; ++r) {
        int qrow = q0 + m * 16 + quad * 4 + r;
        int col = h * HD + nt * 16 + lane16;
        O[(size_t)(b * S_ + qrow) * D_ + col] = f2bf(acc[m][nt][r] / lsum[m][r]);
      }
}

extern "C" void kernel_launch(void* const* d_in, const int* in_sizes, int n_in,
                              void* d_out, int out_size, void* d_ws, size_t ws_size,
                              hipStream_t stream) {
  const float* x  = (const float*)d_in[0];
  const float* fc = (const float*)d_in[1];
  const float* fs = (const float*)d_in[2];
  const float* wq = (const float*)d_in[3];
  const float* wk = (const float*)d_in[4];
  const float* wv = (const float*)d_in[5];
  const float* wo = (const float*)d_in[6];
  float* out = (float*)d_out;

  u16* p = (u16*)d_ws;
  u16* xb    = p; p += (size_t)ROWS * D_;       // 32 MB
  u16* wqkvT = p; p += (size_t)QKV_N * D_;      // 12 MB
  u16* woT   = p; p += (size_t)D_ * D_;         // 8 MB
  u16* qkv   = p; p += (size_t)ROWS * QKV_N;    // 48 MB
  u16* Qr    = p; p += (size_t)ROWS * (NH * HD);   // 32 MB
  u16* Kr    = p; p += (size_t)ROWS * (NKV * HD);  // 8 MB
  u16* Vtr   = p; p += (size_t)ROWS * (NKV * HD);  // 8 MB
  u16* AO    = p; p += (size_t)ROWS * D_;       // 32 MB

  k_cast_x<<<dim3(ROWS * D_ / 1024), dim3(256), 0, stream>>>(x, xb);
  k_wt<<<dim3(64, 64), dim3(32, 8), 0, stream>>>(wq, wqkvT, 2048, 2048);
  k_wt<<<dim3(16, 64), dim3(32, 8), 0, stream>>>(wk, wqkvT + (size_t)2048 * 2048, 2048, 512);
  k_wt<<<dim3(16, 64), dim3(32, 8), 0, stream>>>(wv, wqkvT + (size_t)2560 * 2048, 2048, 512);
  k_wt<<<dim3(64, 64), dim3(32, 8), 0, stream>>>(wo, woT, 2048, 2048);
  k_gemm<QKV_N, false><<<dim3(QKV_N / 128, ROWS / 128), dim3(256), 0, stream>>>(xb, wqkvT, qkv);
  k_rope<<<dim3(ROWS), dim3(256), 0, stream>>>(qkv, fc, fs, Qr, Kr);
  k_vt<<<dim3(B_ * NKV * (S_ / 64)), dim3(256), 0, stream>>>(qkv, Vtr);
  k_attn<<<dim3((S_ / 128) * B_ * NH), dim3(256), 0, stream>>>(Qr, Kr, Vtr, AO);
  k_gemm<D_, true><<<dim3(D_ / 128, ROWS / 128), dim3(256), 0, stream>>>(AO, woT, out);
}

// Round 2
// 516.918 us; speedup vs baseline: 1.1402x; 1.1402x over previous
//
#include <hip/hip_runtime.h>
#include <stdint.h>
#include <stddef.h>

#define B_ 4
#define S_ 2048
#define D_ 2048
#define NH 16
#define NKV 4
#define HD 128
#define QKV_N 3072
#define ROWS (B_*S_)

typedef unsigned short u16;
typedef __attribute__((ext_vector_type(8))) unsigned short u16x8;
typedef __attribute__((ext_vector_type(8))) __bf16 bf16x8;
typedef __attribute__((ext_vector_type(4))) float f32x4;

__device__ __forceinline__ u16 f2bf(float f) {
  unsigned u = __builtin_bit_cast(unsigned, f);
  return (u16)((u + 0x7fffu + ((u >> 16) & 1u)) >> 16);
}
__device__ __forceinline__ u16 f2bf_trunc(float f) {
  return (u16)(__builtin_bit_cast(unsigned, f) >> 16);
}
__device__ __forceinline__ float bf2f(u16 h) {
  return __builtin_bit_cast(float, (unsigned)h << 16);
}
__device__ __forceinline__ f32x4 mfma16(u16x8 a, u16x8 b, f32x4 c) {
  return __builtin_amdgcn_mfma_f32_16x16x32_bf16(
      __builtin_bit_cast(bf16x8, a), __builtin_bit_cast(bf16x8, b), c, 0, 0, 0);
}
__device__ __forceinline__ void gld16(const void* g, void* l) {
  __builtin_amdgcn_global_load_lds(
      (const __attribute__((address_space(1))) void*)g,
      (__attribute__((address_space(3))) void*)l, 16, 0, 0);
}

// ---------- elementwise cast x -> bf16 ----------
__global__ __launch_bounds__(256) void k_cast_x(const float* __restrict__ x, u16* __restrict__ xb) {
  int i = blockIdx.x * 256 + threadIdx.x;
  float4 v = ((const float4*)x)[i];
  union { u16 u[4]; uint2 p; } o;
  o.u[0] = f2bf(v.x); o.u[1] = f2bf(v.y); o.u[2] = f2bf(v.z); o.u[3] = f2bf(v.w);
  ((uint2*)xb)[i] = o.p;
}

// ---------- tiled transpose+cast: w[K][N] fp32 -> wt[N][K(=2048 pitch)] bf16 ----------
__global__ __launch_bounds__(256) void k_wt(const float* __restrict__ w, u16* __restrict__ wt, int K, int N) {
  __shared__ float tile[32][33];
  int kb = blockIdx.y * 32, nb = blockIdx.x * 32;
  int tx = threadIdx.x, ty = threadIdx.y;
#pragma unroll
  for (int j = 0; j < 32; j += 8)
    tile[ty + j][tx] = w[(size_t)(kb + ty + j) * N + nb + tx];
  __syncthreads();
#pragma unroll
  for (int j = 0; j < 32; j += 8)
    wt[(size_t)(nb + ty + j) * K + kb + tx] = f2bf(tile[tx][ty + j]);
}

// ---------- m97-style GEMM: C[M][NT] = A[M][2048] * Bt[NT][2048]^T ----------
template<int NT, bool F32OUT>
__global__ __launch_bounds__(256) void k_gemm(const u16* __restrict__ A, const u16* __restrict__ Bt,
                                              void* __restrict__ C) {
  const int K = 2048;
  __shared__ u16 As[128 * 32];
  __shared__ u16 Bs[128 * 32];
  int mb = blockIdx.y * 128, nb = blockIdx.x * 128;
  int t = threadIdx.x;
  int l = t & 63, lane16 = l & 15, quad = l >> 4;
  int w = t >> 6;
  int wm = (w >> 1) * 64, wn = (w & 1) * 64;
  f32x4 acc[4][4] = {};
  for (int k0 = 0; k0 < K; k0 += 32) {
#pragma unroll
    for (int p = 0; p < 2; ++p) {
      int lin = p * 256 + t;
      int row = lin >> 2, ch = lin & 3;
      gld16(A  + (size_t)(mb + row) * K + k0 + ch * 8, As + (p * 256 + (t & 192)) * 8);
      gld16(Bt + (size_t)(nb + row) * K + k0 + ch * 8, Bs + (p * 256 + (t & 192)) * 8);
    }
    __syncthreads();
    u16x8 af[4], bf[4];
#pragma unroll
    for (int mt = 0; mt < 4; ++mt)
      af[mt] = *(const u16x8*)(As + (wm + mt * 16 + lane16) * 32 + quad * 8);
#pragma unroll
    for (int nt = 0; nt < 4; ++nt)
      bf[nt] = *(const u16x8*)(Bs + (wn + nt * 16 + lane16) * 32 + quad * 8);
#pragma unroll
    for (int mt = 0; mt < 4; ++mt)
#pragma unroll
      for (int nt = 0; nt < 4; ++nt)
        acc[mt][nt] = mfma16(af[mt], bf[nt], acc[mt][nt]);
    __syncthreads();
  }
#pragma unroll
  for (int mt = 0; mt < 4; ++mt)
#pragma unroll
    for (int nt = 0; nt < 4; ++nt)
#pragma unroll
      for (int r = 0; r < 4; ++r) {
        int row = mb + wm + mt * 16 + quad * 4 + r;
        int col = nb + wn + nt * 16 + lane16;
        if constexpr (F32OUT)
          ((float*)C)[(size_t)row * NT + col] = acc[mt][nt][r];
        else
          ((u16*)C)[(size_t)row * NT + col] = f2bf(acc[mt][nt][r]);
      }
}

// ---------- RoPE + scatter; Q pre-scaled by log2(e)/sqrt(HD) ----------
__global__ __launch_bounds__(256) void k_rope(const u16* __restrict__ qkv, const float* __restrict__ fc,
                                              const float* __restrict__ fs, u16* __restrict__ Q,
                                              u16* __restrict__ Kk) {
  const float SC = 0.1275174214f;  // log2(e)/sqrt(128), folded into Q
  int row = blockIdx.x;            // b*S + s
  int b = row >> 11, s = row & 2047;
  int t = threadIdx.x;
#pragma unroll
  for (int j = 0; j < 5; ++j) {
    int p = t + j * 256;           // pair index, 0..1279
    int i = p & 63;
    float c = fc[s * 64 + i], sn = fs[s * 64 + i];
    if (p < 1024) {
      int h = p >> 6;
      unsigned pr = *(const unsigned*)(qkv + (size_t)row * QKV_N + h * 128 + 2 * i);
      float xr = bf2f((u16)(pr & 0xffff)), xi = bf2f((u16)(pr >> 16));
      size_t o = (((size_t)(b * NH + h) * S_) + s) * HD + 2 * i;
      unsigned out = (unsigned)f2bf((xr * c - xi * sn) * SC) |
                     ((unsigned)f2bf((xr * sn + xi * c) * SC) << 16);
      *(unsigned*)(Q + o) = out;
    } else {
      int kh = (p - 1024) >> 6;
      unsigned pr = *(const unsigned*)(qkv + (size_t)row * QKV_N + 2048 + kh * 128 + 2 * i);
      float xr = bf2f((u16)(pr & 0xffff)), xi = bf2f((u16)(pr >> 16));
      size_t o = (((size_t)(b * NKV + kh) * S_) + s) * HD + 2 * i;
      unsigned out = (unsigned)f2bf(xr * c - xi * sn) | ((unsigned)f2bf(xr * sn + xi * c) << 16);
      *(unsigned*)(Kk + o) = out;
    }
  }
}

// ---------- V transpose: qkv[.,2560+kh*128+d] -> Vt[b][kh][d][s] ----------
__global__ __launch_bounds__(256) void k_vt(const u16* __restrict__ qkv, u16* __restrict__ Vt) {
  int blk = blockIdx.x;            // b*128 + kh*32 + sb
  int sb = blk & 31, kh = (blk >> 5) & 3, b = blk >> 7;
  int t = threadIdx.x;
  int d = t >> 1, sc = t & 1;
  int s0 = sb * 64 + sc * 32;
  u16 tmp[32];
#pragma unroll
  for (int i = 0; i < 32; ++i)
    tmp[i] = qkv[(size_t)(b * S_ + s0 + i) * QKV_N + 2560 + kh * 128 + d];
  size_t o = ((size_t)(b * NKV + kh) * HD + d) * S_ + s0;
#pragma unroll
  for (int i = 0; i < 32; i += 8)
    *(u16x8*)(Vt + o + i) = *(const u16x8*)(tmp + i);
}

// ---------- flash attention v2: Bc=64, paired q-tiles, ones-sum, swizzled async staging ----------
__global__ __launch_bounds__(256) void k_attn(const u16* __restrict__ Q, const u16* __restrict__ Kg,
                                              const u16* __restrict__ Vt, u16* __restrict__ O) {
  int bx = blockIdx.x;
  int bh = bx >> 3, pr = bx & 7;
  int b = bh >> 4, h = bh & 15, kh = h >> 2;
  int t = threadIdx.x;
  int w = t >> 6, l = t & 63, L = l & 15, quad = l >> 4;

  __shared__ u16 Ks[64 * 128];        // [key][d], chunk-swizzled: chunk ^= key&7
  __shared__ u16 Vs[144 * 64];        // [d][key], chunk ^= d&7; rows 128..143 = ones
  __shared__ u16 Ps[4][32 * 72];      // per-wave P, pitch 72
  u16* Pw = &Ps[w][0];

  const u16* Qh = Q  + ((size_t)(b * NH  + h ) * S_) * HD;
  const u16* Kh = Kg + ((size_t)(b * NKV + kh) * S_) * HD;
  const u16* Vh = Vt + ((size_t)(b * NKV + kh) * HD) * S_;

  // ones rows for the row-sum trick (persist across tiles; d-loop only writes d<128)
  if (t < 128) {
    u16x8 ones;
#pragma unroll
    for (int i = 0; i < 8; ++i) ones[i] = 0x3F80;
    *(u16x8*)(Vs + 128 * 64 + t * 8) = ones;
  }

#pragma unroll 1
  for (int half = 0; half < 2; ++half) {
    int qb = half ? (15 - pr) : pr;
    int q0 = qb * 128 + w * 32;

    u16x8 qf[2][4];
#pragma unroll
    for (int m = 0; m < 2; ++m)
#pragma unroll
      for (int kk = 0; kk < 4; ++kk)
        qf[m][kk] = *(const u16x8*)(Qh + (size_t)(q0 + m * 16 + L) * HD + kk * 32 + quad * 8);

    f32x4 acc[2][9] = {};
    int ktiles = 2 * qb + 2;
#pragma unroll 1
    for (int kt = 0; kt < ktiles; ++kt) {
      int kbase = kt * 64;
      __syncthreads();
      // stage K tile (64x128) via async DMA, global-side chunk swizzle
#pragma unroll
      for (int i = 0; i < 4; ++i) {
        int lin = i * 256 + t;
        int row = lin >> 4, c = lin & 15;
        gld16(Kh + (size_t)(kbase + row) * HD + ((c ^ (row & 7)) * 8),
              Ks + (i * 256 + (t & 192)) * 8);
      }
      // stage V^T tile (128 d x 64 keys)
#pragma unroll
      for (int i = 0; i < 4; ++i) {
        int lin = i * 256 + t;
        int d = lin >> 3, c = lin & 7;
        gld16(Vh + (size_t)d * S_ + kbase + ((c ^ (d & 7)) * 8),
              Vs + (i * 256 + (t & 192)) * 8);
      }
      __syncthreads();
      if (kbase > q0 + 31) continue;   // fully-masked for this wave; barriers stay uniform

      // S = Q K^T  (scale pre-folded into Q)
      f32x4 s[2][4] = {};
#pragma unroll
      for (int n = 0; n < 4; ++n)
#pragma unroll
        for (int kk = 0; kk < 4; ++kk) {
          int key = n * 16 + L;
          u16x8 kf = *(const u16x8*)(Ks + key * 128 + (((kk * 4 + quad) ^ (L & 7)) * 8));
          s[0][n] = mfma16(qf[0][kk], kf, s[0][n]);
          s[1][n] = mfma16(qf[1][kk], kf, s[1][n]);
        }
      // exp2 + (diag-only) mask + truncated P store
      bool needMask = (kbase + 63 > q0);
#pragma unroll
      for (int m = 0; m < 2; ++m)
#pragma unroll
        for (int n = 0; n < 4; ++n)
#pragma unroll
          for (int r = 0; r < 4; ++r) {
            float e = exp2f(s[m][n][r]);
            if (needMask) {
              int key = kbase + n * 16 + L;
              int qrow = q0 + m * 16 + quad * 4 + r;
              e = (key <= qrow) ? e : 0.0f;
            }
            Pw[(m * 16 + quad * 4 + r) * 72 + n * 16 + L] = f2bf_trunc(e);
          }
      // O += P V  (wave-private P; no barrier needed)
#pragma unroll
      for (int kc = 0; kc < 2; ++kc) {
        u16x8 pf0 = *(const u16x8*)(Pw + L * 72 + kc * 32 + quad * 8);
        u16x8 pf1 = *(const u16x8*)(Pw + (16 + L) * 72 + kc * 32 + quad * 8);
#pragma unroll
        for (int nt = 0; nt < 9; ++nt) {
          int d = nt * 16 + L;
          u16x8 vf = *(const u16x8*)(Vs + d * 64 + (((kc * 4 + quad) ^ (L & 7)) * 8));
          acc[0][nt] = mfma16(pf0, vf, acc[0][nt]);
          acc[1][nt] = mfma16(pf1, vf, acc[1][nt]);
        }
      }
    }
    // epilogue: normalize by ones-column sums (acc[m][8]), write [b][s][h*128+d]
#pragma unroll
    for (int m = 0; m < 2; ++m)
#pragma unroll
      for (int r = 0; r < 4; ++r) {
        float inv = 1.0f / acc[m][8][r];
        int qrow = q0 + m * 16 + quad * 4 + r;
#pragma unroll
        for (int nt = 0; nt < 8; ++nt) {
          int col = h * HD + nt * 16 + L;
          O[(size_t)(b * S_ + qrow) * D_ + col] = f2bf(acc[m][nt][r] * inv);
        }
      }
  }
}

extern "C" void kernel_launch(void* const* d_in, const int* in_sizes, int n_in,
                              void* d_out, int out_size, void* d_ws, size_t ws_size,
                              hipStream_t stream) {
  const float* x  = (const float*)d_in[0];
  const float* fc = (const float*)d_in[1];
  const float* fs = (const float*)d_in[2];
  const float* wq = (const float*)d_in[3];
  const float* wk = (const float*)d_in[4];
  const float* wv = (const float*)d_in[5];
  const float* wo = (const float*)d_in[6];
  float* out = (float*)d_out;

  u16* p = (u16*)d_ws;
  u16* xb    = p; p += (size_t)ROWS * D_;
  u16* wqkvT = p; p += (size_t)QKV_N * D_;
  u16* woT   = p; p += (size_t)D_ * D_;
  u16* qkv   = p; p += (size_t)ROWS * QKV_N;
  u16* Qr    = p; p += (size_t)ROWS * (NH * HD);
  u16* Kr    = p; p += (size_t)ROWS * (NKV * HD);
  u16* Vtr   = p; p += (size_t)ROWS * (NKV * HD);
  u16* AO    = p; p += (size_t)ROWS * D_;

  k_cast_x<<<dim3(ROWS * D_ / 1024), dim3(256), 0, stream>>>(x, xb);
  k_wt<<<dim3(64, 64), dim3(32, 8), 0, stream>>>(wq, wqkvT, 2048, 2048);
  k_wt<<<dim3(16, 64), dim3(32, 8), 0, stream>>>(wk, wqkvT + (size_t)2048 * 2048, 2048, 512);
  k_wt<<<dim3(16, 64), dim3(32, 8), 0, stream>>>(wv, wqkvT + (size_t)2560 * 2048, 2048, 512);
  k_wt<<<dim3(64, 64), dim3(32, 8), 0, stream>>>(wo, woT, 2048, 2048);
  k_gemm<QKV_N, false><<<dim3(QKV_N / 128, ROWS / 128), dim3(256), 0, stream>>>(xb, wqkvT, qkv);
  k_rope<<<dim3(ROWS), dim3(256), 0, stream>>>(qkv, fc, fs, Qr, Kr);
  k_vt<<<dim3(B_ * NKV * (S_ / 64)), dim3(256), 0, stream>>>(qkv, Vtr);
  k_attn<<<dim3(64 * 8), dim3(256), 0, stream>>>(Qr, Kr, Vtr, AO);
  k_gemm<D_, true><<<dim3(D_ / 128, ROWS / 128), dim3(256), 0, stream>>>(AO, woT, out);
}